// Round 7
// baseline (77.558 us; speedup 1.0000x reference)
//
#include <hip/hip_runtime.h>

// Binary successive-approximation encoder:
//   v = clip(x,0,1); bit i of floor(v*2^n) (clamped to 2^n-1) reproduces the
//   reference's successive subtraction exactly (all pow2 ops exact in fp32).
// x: [16,1024,512] f32 -> out: [16,1024,n_bits,512] f32.
//
// R7: TWO-KERNEL READ/WRITE SEPARATION. All within-kernel interleave grains
// (R1 scatter, R5 linear, R6 16-row bursts) landed 73-78us ~ 5.0 TB/s, while
// pure-write fill sustains 6.9 TB/s on this chip. Last untested grain: kernel-
// level. K1 compresses x -> 10-bit codes (u16) in d_ws (33.5MB R + 16.8MB W).
// K2 expands codes -> out: reads 16.8MB that K1 just wrote (L3-resident, no
// HBM fetch) and emits a pure 335.5MB write stream, fill-shaped.
// Same-stream kernel boundary gives release/acquire (L2 flush) -> K2 sees K1's
// codes; codes stay hot in the 256MB memory-side L3.
// Fallback: single-kernel R5 path if ws_size < 2 bytes/elem.

#define C_DIM 512
#define C4    128   // C_DIM / 4

typedef float  f32x4 __attribute__((ext_vector_type(4)));
typedef unsigned short u16;
typedef u16    u16x4 __attribute__((ext_vector_type(4)));

// ---- K1: x -> packed codes (one thread per 4 elements) ----
__global__ __launch_bounds__(256) void binenc_pack(const float* __restrict__ x,
                                                   const int* __restrict__ n_bits_p,
                                                   u16* __restrict__ codes,
                                                   int n_vec) {
    const int n_bits = *n_bits_p;
    const float scale = (float)(1u << n_bits);
    const int   maxq  = (1 << n_bits) - 1;

    const int vid = blockIdx.x * blockDim.x + threadIdx.x;
    if (vid >= n_vec) return;

    const f32x4 xv = reinterpret_cast<const f32x4*>(x)[vid];
    u16x4 c;
#pragma unroll
    for (int j = 0; j < 4; ++j) {
        float v  = fminf(fmaxf(xv[j], 0.0f), 1.0f);   // jnp.clip, exact
        int   qi = (int)(v * scale);                  // exact pow2 scale + trunc
        c[j] = (u16)(qi > maxq ? maxq : qi);          // v==1.0 -> all bits set
    }
    reinterpret_cast<u16x4*>(codes)[vid] = c;
}

// ---- K2: codes -> out, pure write stream (R5 linear map) ----
// block = row; tid: c4 = tid&127 (channel float4), bit0 = tid>>7 (bit parity);
// output float4 slot k*256+tid == (2k+bit0)*128 + c4 -> byte-sequential in k.
__global__ __launch_bounds__(256) void binenc_expand(const u16* __restrict__ codes,
                                                     const int* __restrict__ n_bits_p,
                                                     float* __restrict__ out) {
    const int n_bits = *n_bits_p;
    const int row  = blockIdx.x;
    const int tid  = threadIdx.x;
    const int c4   = tid & (C4 - 1);
    const int bit0 = tid >> 7;

    const u16x4 q = reinterpret_cast<const u16x4*>(codes)[row * C4 + c4];

    f32x4* rowbase = reinterpret_cast<f32x4*>(out) + (size_t)row * n_bits * C4;
#pragma unroll 5
    for (int k = 0; 2 * k + bit0 < n_bits; ++k) {
        const int sh = n_bits - 1 - (2 * k + bit0);
        f32x4 s;
#pragma unroll
        for (int j = 0; j < 4; ++j)
            s[j] = (float)((q[j] >> sh) & 1);
        rowbase[k * 256 + tid] = s;
    }
}

// ---- fallback: R5 single-kernel (best single-kernel variant, 73.2us) ----
__global__ __launch_bounds__(256) void binenc_fused(const float* __restrict__ x,
                                                    const int* __restrict__ n_bits_p,
                                                    float* __restrict__ out) {
    const int n_bits = *n_bits_p;
    const float scale = (float)(1u << n_bits);
    const int   maxq  = (1 << n_bits) - 1;

    const int row  = blockIdx.x;
    const int tid  = threadIdx.x;
    const int c4   = tid & (C4 - 1);
    const int bit0 = tid >> 7;

    const f32x4 xv = reinterpret_cast<const f32x4*>(x)[row * C4 + c4];
    int q[4];
#pragma unroll
    for (int j = 0; j < 4; ++j) {
        float v  = fminf(fmaxf(xv[j], 0.0f), 1.0f);
        int   qi = (int)(v * scale);
        q[j] = qi > maxq ? maxq : qi;
    }

    f32x4* rowbase = reinterpret_cast<f32x4*>(out) + (size_t)row * n_bits * C4;
#pragma unroll 5
    for (int k = 0; 2 * k + bit0 < n_bits; ++k) {
        const int sh = n_bits - 1 - (2 * k + bit0);
        f32x4 s;
#pragma unroll
        for (int j = 0; j < 4; ++j)
            s[j] = (float)((q[j] >> sh) & 1);
        rowbase[k * 256 + tid] = s;
    }
}

extern "C" void kernel_launch(void* const* d_in, const int* in_sizes, int n_in,
                              void* d_out, int out_size, void* d_ws, size_t ws_size,
                              hipStream_t stream) {
    const float* x        = (const float*)d_in[0];
    const int*   n_bits_p = (const int*)d_in[1];
    float*       out      = (float*)d_out;

    const int n_elems = in_sizes[0];          // 16*1024*512 = 8,388,608
    const int n_rows  = n_elems / C_DIM;      // 16384
    const int block   = 256;

    if (ws_size >= (size_t)n_elems * sizeof(u16)) {
        u16* codes = (u16*)d_ws;
        const int n_vec = n_elems >> 2;
        binenc_pack<<<(n_vec + block - 1) / block, block, 0, stream>>>(x, n_bits_p, codes, n_vec);
        binenc_expand<<<n_rows, block, 0, stream>>>(codes, n_bits_p, out);
    } else {
        binenc_fused<<<n_rows, block, 0, stream>>>(x, n_bits_p, out);
    }
}

// Round 8
// 64.636 us; speedup vs baseline: 1.1999x; 1.1999x over previous
//
#include <hip/hip_runtime.h>

// Binary successive-approximation encoder:
//   v = clip(x,0,1); bit i of floor(v*2^n) (clamped to 2^n-1) reproduces the
//   reference's successive subtraction exactly (all pow2 ops exact in fp32).
// x: [16,1024,512] f32 -> out: [16,1024,n_bits,512] f32.
//
// R8: R5 linear-write map + NONTEMPORAL STORES ONLY (loads stay cached).
// Rationale: all interleave restructurings (R1/R5/R6/R7) pinned at ~5.0 TB/s
// while pure-write fill hits 6.9. Last mechanistic difference: normal stores
// drain via L2 eviction order (set-indexed, 8 split XCD L2s) -> DRAM page
// thrash; nt stores bypass L2 retention and reach memory in issue order,
// which IS monotone under this thread map. R3's nt test was confounded
// (nt on the L3-resident input load + scattered 2KB-stride stores).
//
// Thread map (R5): block = row (b*T+t), 256 thr; c4 = tid&127 picks the input
// float4, bit0 = tid>>7 picks bit parity; output float4 slot k*256+tid ==
// (2k+bit0)*128 + c4 -> stores walk the row byte-sequentially as k increases.

#define C_DIM 512
#define C4    128   // C_DIM / 4

typedef float f32x4 __attribute__((ext_vector_type(4)));

__global__ __launch_bounds__(256) void binenc_kernel(const float* __restrict__ x,
                                                     const int* __restrict__ n_bits_p,
                                                     float* __restrict__ out) {
    const int n_bits = *n_bits_p;
    const float scale = (float)(1u << n_bits);
    const int   maxq  = (1 << n_bits) - 1;

    const int row  = blockIdx.x;
    const int tid  = threadIdx.x;
    const int c4   = tid & (C4 - 1);   // input float4 within the row
    const int bit0 = tid >> 7;         // bit parity this thread writes

    // Cached load: 33.5 MB input is L3-resident across graph replays.
    const f32x4 xv = reinterpret_cast<const f32x4*>(x)[row * C4 + c4];

    int q[4];
#pragma unroll
    for (int j = 0; j < 4; ++j) {
        float v  = fminf(fmaxf(xv[j], 0.0f), 1.0f);   // jnp.clip, exact
        int   qi = (int)(v * scale);                  // exact pow2 scale + trunc
        q[j] = qi > maxq ? maxq : qi;                 // v==1.0 -> all bits set
    }

    f32x4* rowbase = reinterpret_cast<f32x4*>(out) + (size_t)row * n_bits * C4;
#pragma unroll 5
    for (int k = 0; 2 * k + bit0 < n_bits; ++k) {
        const int sh = n_bits - 1 - (2 * k + bit0);
        f32x4 s;
#pragma unroll
        for (int j = 0; j < 4; ++j)
            s[j] = (float)((q[j] >> sh) & 1);
        __builtin_nontemporal_store(s, rowbase + k * 256 + tid);
    }
}

extern "C" void kernel_launch(void* const* d_in, const int* in_sizes, int n_in,
                              void* d_out, int out_size, void* d_ws, size_t ws_size,
                              hipStream_t stream) {
    const float* x        = (const float*)d_in[0];
    const int*   n_bits_p = (const int*)d_in[1];
    float*       out      = (float*)d_out;

    const int n_rows = in_sizes[0] / C_DIM;   // 16*1024 = 16384 rows
    const int block  = 256;

    binenc_kernel<<<n_rows, block, 0, stream>>>(x, n_bits_p, out);
}